// Round 8
// baseline (1308.206 us; speedup 1.0000x reference)
//
#include <hip/hip_runtime.h>
#include <stdint.h>

#define Ln 4
#define Bn 8
#define Sn 2048
#define Hn 1024
#define NHn 2
#define DHn 512
#define NSn 32
#define Mn (Bn*Sn)

typedef __attribute__((ext_vector_type(8))) short bf16x8;
typedef __attribute__((ext_vector_type(4))) float f32x4;
typedef unsigned short u16;

__device__ __forceinline__ float bf2f(u16 u){
  union { unsigned int i; float f; } c; c.i = ((unsigned int)u)<<16; return c.f;
}
__device__ __forceinline__ u16 f2bf(float f){
  union { float f; unsigned int i; } c; c.f = f;
  unsigned int r = c.i + 0x7FFFu + ((c.i>>16)&1u);
  return (u16)(r>>16);
}
__device__ __forceinline__ uint32_t packbf(float a, float b){
  return (uint32_t)f2bf(a) | ((uint32_t)f2bf(b)<<16);
}
__device__ __forceinline__ void gl2lds16(const void* g, void* l){
  __builtin_amdgcn_global_load_lds((const __attribute__((address_space(1))) void*)g,
                                   (__attribute__((address_space(3))) void*)l, 16, 0, 0);
}

__device__ __forceinline__ float block_sum256(float v, float* red){
#pragma unroll
  for (int m=32;m>=1;m>>=1) v += __shfl_xor(v, m, 64);
  int tid = threadIdx.x;
  if ((tid&63)==0) red[tid>>6] = v;
  __syncthreads();
  v = red[0]+red[1]+red[2]+red[3];
  __syncthreads();
  return v;
}

// ---------------- weight f32 -> bf16 ----------------
__global__ __launch_bounds__(256) void convw_kernel(const float* __restrict__ Wq, const float* __restrict__ Wk,
    const float* __restrict__ Wv, const float* __restrict__ Wo, u16* __restrict__ wb){
  int m = blockIdx.y;
  const float* src = (m==0)?Wq:(m==1)?Wk:(m==2)?Wv:Wo;
  size_t i = ((size_t)blockIdx.x*256 + threadIdx.x)*4;
  const float4 v = *(const float4*)&src[i];
  ushort4 o;
  o.x=f2bf(v.x); o.y=f2bf(v.y); o.z=f2bf(v.z); o.w=f2bf(v.w);
  *(ushort4*)&wb[(size_t)m*Hn*Hn + i] = o;
}

// ---------------- layer mix + LN1 -> x (bf16) ----------------
__global__ __launch_bounds__(256) void mixln_kernel(const float* __restrict__ hs, const float* __restrict__ lw,
    const float* __restrict__ g, const float* __restrict__ be, u16* __restrict__ xb){
  __shared__ float red[4];
  int row = blockIdx.x;
  int tid = threadIdx.x;
  float l0=lw[0], l1=lw[1], l2=lw[2], l3=lw[3];
  float mx = fmaxf(fmaxf(l0,l1),fmaxf(l2,l3));
  float e0=__expf(l0-mx), e1=__expf(l1-mx), e2=__expf(l2-mx), e3=__expf(l3-mx);
  float inv = 1.0f/(e0+e1+e2+e3);
  e0*=inv; e1*=inv; e2*=inv; e3*=inv;
  size_t base = (size_t)row*Hn + tid*4;
  const float4 h0 = *(const float4*)&hs[base];
  const float4 h1 = *(const float4*)&hs[base + (size_t)Mn*Hn];
  const float4 h2 = *(const float4*)&hs[base + (size_t)2*Mn*Hn];
  const float4 h3 = *(const float4*)&hs[base + (size_t)3*Mn*Hn];
  float x0 = e0*h0.x + e1*h1.x + e2*h2.x + e3*h3.x;
  float x1 = e0*h0.y + e1*h1.y + e2*h2.y + e3*h3.y;
  float x2 = e0*h0.z + e1*h1.z + e2*h2.z + e3*h3.z;
  float x3 = e0*h0.w + e1*h1.w + e2*h2.w + e3*h3.w;
  float s = block_sum256(x0+x1+x2+x3, red);
  float mean = s * (1.0f/Hn);
  float d0=x0-mean, d1=x1-mean, d2=x2-mean, d3=x3-mean;
  float sq = block_sum256(d0*d0+d1*d1+d2*d2+d3*d3, red);
  float rstd = rsqrtf(sq*(1.0f/Hn) + 1e-7f);
  int c = tid*4;
  ushort4 o;
  o.x = f2bf(d0*rstd*g[c+0] + be[c+0]);
  o.y = f2bf(d1*rstd*g[c+1] + be[c+1]);
  o.z = f2bf(d2*rstd*g[c+2] + be[c+2]);
  o.w = f2bf(d3*rstd*g[c+3] + be[c+3]);
  *(ushort4*)&xb[(size_t)row*Hn + c] = o;
}

// ---------------- GEMM 256x256 tile, BK=64, 8 waves, phase-split ----------------
template<int MODE>
__global__ __launch_bounds__(512,2) void gemm256_kernel(const u16* __restrict__ A, const u16* __restrict__ Bw,
    const float* __restrict__ bias, const u16* __restrict__ resid, void* __restrict__ Cout, float scale){
  __shared__ char lds[2][2][32768];   // [buf][A/B][256 rows x 64 cols bf16]
  int tid = threadIdx.x, lane = tid&63, wid = tid>>6;
  int ln = lane&15, g4 = lane>>4;
  int wm = wid>>2, wn = wid&3;        // wave grid 2M x 4N; per-wave out 128x64
  int swz = (blockIdx.x&7)*32 + (blockIdx.x>>3);
  int i0 = (swz>>2)*256;
  int j0 = (swz&3)*256;

  f32x4 acc[8][4];
#pragma unroll
  for (int a=0;a<8;a++)
#pragma unroll
    for (int b=0;b<4;b++) acc[a][b] = (f32x4){0.f,0.f,0.f,0.f};

  const u16* Asrc = A + (size_t)i0*Hn;
  const u16* Bsrc = Bw + (size_t)j0*Hn;

#define STAGE1(SRC, DST, G) do { \
    int g_ = (G); int row_ = g_>>3; int cs_ = (g_&7) ^ (row_&7); \
    gl2lds16((SRC) + (size_t)row_*Hn + cs_*8, (DST) + g_*16); } while(0)

#define RD(BASE, ROW, KG) (*(const bf16x8*)((BASE) + (ROW)*128 + ((((KG)) ^ ((ROW)&7))<<4)))

  {
    const u16* An_ = Asrc; const u16* Bn_ = Bsrc;
#pragma unroll
    for (int c=0;c<4;++c){ STAGE1(An_, lds[0][0], tid + c*512); }
#pragma unroll
    for (int c=0;c<4;++c){ STAGE1(Bn_, lds[0][1], tid + c*512); }
  }
  __syncthreads();

  bf16x8 af[4][2], bf0[2][2], bf1[2][2];

#pragma unroll 1
  for (int t=0; t<16; ++t){
    const char* Ac = lds[t&1][0];
    const char* Bc = lds[t&1][1];
    char* Anx = lds[(t+1)&1][0];
    char* Bnx = lds[(t+1)&1][1];
    const u16* An_ = Asrc + (t+1)*64;
    const u16* Bn_ = Bsrc + (t+1)*64;
    bool st = (t < 15);
    if (st){ STAGE1(An_, Anx, tid); STAGE1(An_, Anx, tid+512); STAGE1(Bn_, Bnx, tid); }
#pragma unroll
    for (int mt=0; mt<4; ++mt)
#pragma unroll
      for (int kk=0; kk<2; ++kk) af[mt][kk] = RD(Ac, wm*128 + mt*16 + ln, kk*4+g4);
#pragma unroll
    for (int nt=0; nt<2; ++nt)
#pragma unroll
      for (int kk=0; kk<2; ++kk) bf0[nt][kk] = RD(Bc, wn*64 + nt*16 + ln, kk*4+g4);
    __builtin_amdgcn_s_barrier();
    __builtin_amdgcn_s_setprio(1);
#pragma unroll
    for (int kk=0; kk<2; ++kk)
#pragma unroll
      for (int mt=0; mt<4; ++mt)
#pragma unroll
        for (int nt=0; nt<2; ++nt)
          acc[mt][nt] = __builtin_amdgcn_mfma_f32_16x16x32_bf16(af[mt][kk], bf0[nt][kk], acc[mt][nt], 0,0,0);
    __builtin_amdgcn_s_setprio(0);
    if (st){ STAGE1(Bn_, Bnx, tid+512); STAGE1(An_, Anx, tid+1024); STAGE1(An_, Anx, tid+1536); }
#pragma unroll
    for (int nt=0; nt<2; ++nt)
#pragma unroll
      for (int kk=0; kk<2; ++kk) bf1[nt][kk] = RD(Bc, wn*64 + (2+nt)*16 + ln, kk*4+g4);
    __builtin_amdgcn_s_barrier();
    __builtin_amdgcn_s_setprio(1);
#pragma unroll
    for (int kk=0; kk<2; ++kk)
#pragma unroll
      for (int mt=0; mt<4; ++mt)
#pragma unroll
        for (int nt=0; nt<2; ++nt)
          acc[mt][2+nt] = __builtin_amdgcn_mfma_f32_16x16x32_bf16(af[mt][kk], bf1[nt][kk], acc[mt][2+nt], 0,0,0);
    __builtin_amdgcn_s_setprio(0);
    if (st){ STAGE1(Bn_, Bnx, tid+1024); STAGE1(Bn_, Bnx, tid+1536); }
#pragma unroll
    for (int mt=0; mt<4; ++mt)
#pragma unroll
      for (int kk=0; kk<2; ++kk) af[mt][kk] = RD(Ac, wm*128 + 64 + mt*16 + ln, kk*4+g4);
    __builtin_amdgcn_s_barrier();
    __builtin_amdgcn_s_setprio(1);
#pragma unroll
    for (int kk=0; kk<2; ++kk)
#pragma unroll
      for (int mt=0; mt<4; ++mt)
#pragma unroll
        for (int nt=0; nt<2; ++nt)
          acc[4+mt][nt] = __builtin_amdgcn_mfma_f32_16x16x32_bf16(af[mt][kk], bf0[nt][kk], acc[4+mt][nt], 0,0,0);
    __builtin_amdgcn_s_setprio(0);
    __builtin_amdgcn_s_barrier();
    __builtin_amdgcn_s_setprio(1);
#pragma unroll
    for (int kk=0; kk<2; ++kk)
#pragma unroll
      for (int mt=0; mt<4; ++mt)
#pragma unroll
        for (int nt=0; nt<2; ++nt)
          acc[4+mt][2+nt] = __builtin_amdgcn_mfma_f32_16x16x32_bf16(af[mt][kk], bf1[nt][kk], acc[4+mt][2+nt], 0,0,0);
    __builtin_amdgcn_s_setprio(0);
    __syncthreads();
  }
#undef STAGE1
#undef RD

#pragma unroll
  for (int mt=0; mt<8; ++mt){
#pragma unroll
    for (int nt=0; nt<4; ++nt){
#pragma unroll
      for (int r=0; r<4; ++r){
        int i = i0 + wm*128 + mt*16 + g4*4 + r;
        int j = j0 + wn*64 + nt*16 + ln;
        float v = acc[mt][nt][r] + bias[j];
        if (MODE==0){
          int b = i>>11, s = i&2047, nh = j>>9, dh = j&511;
          ((u16*)Cout)[(((size_t)(b*NHn+nh)*Sn + s)<<9) + dh] = f2bf(v*scale);
        } else if (MODE==1){
          int b = i>>11, s = i&2047, nh = j>>9, dh = j&511;
          ((u16*)Cout)[((size_t)((b*NHn+nh)*(Sn/32) + (s>>5))<<14) + (dh<<5) + (s&31)] = f2bf(v);
        } else {
          float res = bf2f(resid[(size_t)i*Hn + j]);
          ((float*)Cout)[(size_t)i*Hn + j] = v + res;
        }
      }
    }
  }
}

// ---------------- flash attention ----------------
// 4 waves x 16 q = 64 q/block; 512 blocks -> 2 INDEPENDENT blocks/CU
// (two barrier groups overlap each other's stalls). K double-buffered in LDS
// (64KB); V prefetched into REGISTERS per-wave d-slice (8 frags, issued
// iter-start/post-QK, consumed in PV — latency hidden, no LDS). P block-shared
// (4KB). d-split PV: wave owns d-slice wid*128..+127 for ALL 64 q.
__global__ __launch_bounds__(256,2) void attn_kernel(const u16* __restrict__ qb, const u16* __restrict__ kb,
    const u16* __restrict__ vt, const int* __restrict__ mask, u16* __restrict__ ctx){
  __shared__ u16 Ks[2][32*512];  // 2x32KB, row-swizzled
  __shared__ u16 Ps[4*16*32];    // block-shared P[64q][32k], wave-region + granule-swizzled
  __shared__ float Lcorr[64];    // per-q rescale factor (1.0 if none)
  __shared__ float Lflag[4];     // per-wave rescale flag
  __shared__ float Linv[64];     // per-q 1/l (epilogue)
  int tid = threadIdx.x, lane = tid&63, wid = tid>>6;   // wid 0..3
  int ln = lane&15, g4 = lane>>4;
  int gid = blockIdx.x;
  int xcd = gid&7, ord = gid>>3;            // ord 0..63
  int bh = xcd*2 + (ord>>5), qt = ord&31;   // 32 qt-blocks of one bh share an XCD
  int b = bh >> 1, nh = bh & 1;
  u16* pw = Ps + wid*512;
  uint32_t* pw32 = (uint32_t*)pw;
  const int swz = (ln&7)<<4;
  const int rsw = (ln>>1)&3;     // P swizzle key

  bf16x8 aq[16];
  size_t qoff = ((size_t)bh*Sn + qt*64 + wid*16 + ln)*DHn + g4*8;
#pragma unroll
  for (int ch=0; ch<16; ++ch) aq[ch] = *(const bf16x8*)&qb[qoff + ch*32];

  // o2[qf][df]: q = qf*16 + g4*4 + r ; d = wid*128 + df*16 + ln
  f32x4 o2[4][8];
#pragma unroll
  for (int qf=0; qf<4; ++qf)
#pragma unroll
    for (int df=0; df<8; ++df) o2[qf][df] = (f32x4){0.f,0.f,0.f,0.f};
  float mrun = -1e30f, lrun = 0.f;

  const size_t kbase = (size_t)bh*Sn*DHn;
  // V^T tiled layout [kt][512 d][32 k]; this wave's d-slice fragment base:
  const u16* vbase = vt + (size_t)bh*Sn*DHn + (wid*128 + ln)*32 + g4*8;

#define STAGE_K(KT,BUF) do { \
  _Pragma("unroll") \
  for (int t_=0; t_<8; ++t_){ \
    int krow_ = t_*4 + wid; \
    int koff_ = (lane*16) ^ ((krow_&7)<<4); \
    gl2lds16(&kb[kbase + ((size_t)((KT)*32 + krow_))*DHn + (koff_>>1)], \
             (char*)Ks[BUF] + krow_*1024 + lane*16); \
  } } while(0)

  STAGE_K(0,0);
  __syncthreads();   // tile 0 resident
#pragma unroll 1
  for (int kt=0; kt<Sn/32; ++kt){
    int cur = kt&1;
    if (kt < Sn/32 - 1) STAGE_K(kt+1, cur^1);   // DMA spans whole iter; drained at end sync
    const u16* vkt = vbase + kt*16384;
    bf16x8 vf[8];
#pragma unroll
    for (int df=0; df<4; ++df) vf[df] = *(const bf16x8*)(vkt + df*512);   // early V batch
    const char* KsB = (const char*)Ks[cur];
    f32x4 s0 = (f32x4){0.f,0.f,0.f,0.f};
    f32x4 s1 = (f32x4){0.f,0.f,0.f,0.f};
#pragma unroll
    for (int ch=0; ch<16; ++ch){
      bf16x8 k0 = *(const bf16x8*)(KsB + ln*1024      + ((ch*64 + g4*16) ^ swz));
      bf16x8 k1 = *(const bf16x8*)(KsB + (16+ln)*1024 + ((ch*64 + g4*16) ^ swz));
      s0 = __builtin_amdgcn_mfma_f32_16x16x32_bf16(k0, aq[ch], s0, 0,0,0);
      s1 = __builtin_amdgcn_mfma_f32_16x16x32_bf16(k1, aq[ch], s1, 0,0,0);
    }
#pragma unroll
    for (int df=4; df<8; ++df) vf[df] = *(const bf16x8*)(vkt + df*512);   // late V batch (covered by softmax+barrier)
    int4 mk0 = *(const int4*)&mask[b*Sn + kt*32 + g4*4];
    int4 mk1 = *(const int4*)&mask[b*Sn + kt*32 + 16 + g4*4];
    s0[0] += (float)(1-mk0.x)*-10000.0f; s0[1] += (float)(1-mk0.y)*-10000.0f;
    s0[2] += (float)(1-mk0.z)*-10000.0f; s0[3] += (float)(1-mk0.w)*-10000.0f;
    s1[0] += (float)(1-mk1.x)*-10000.0f; s1[1] += (float)(1-mk1.y)*-10000.0f;
    s1[2] += (float)(1-mk1.z)*-10000.0f; s1[3] += (float)(1-mk1.w)*-10000.0f;
    float tmax = fmaxf(fmaxf(fmaxf(s0[0],s0[1]),fmaxf(s0[2],s0[3])),
                       fmaxf(fmaxf(s1[0],s1[1]),fmaxf(s1[2],s1[3])));
    tmax = fmaxf(tmax, __shfl_xor(tmax, 16));
    tmax = fmaxf(tmax, __shfl_xor(tmax, 32));
    float corr = 1.0f, wflag = 0.0f;
    if (__any(tmax > mrun + 8.0f)){     // defer-max: rare rescale
      float nm = fmaxf(mrun, tmax);
      corr = __expf(mrun - nm);
      mrun = nm; lrun *= corr;
      wflag = 1.0f;
    }
    float p0=__expf(s0[0]-mrun), p1=__expf(s0[1]-mrun), p2=__expf(s0[2]-mrun), p3=__expf(s0[3]-mrun);
    float p4=__expf(s1[0]-mrun), p5=__expf(s1[1]-mrun), p6=__expf(s1[2]-mrun), p7=__expf(s1[3]-mrun);
    float sum = ((p0+p1)+(p2+p3)) + ((p4+p5)+(p6+p7));
    sum += __shfl_xor(sum, 16);
    sum += __shfl_xor(sum, 32);
    lrun += sum;
    // P write: swizzled granules — granule (q,gr) at u16 q*32 + (gr^((q>>1)&3))*8.
    {
      int base = ln*16 + ((g4&1)<<1);
      pw32[base + (((g4>>1)    ^rsw)<<2)    ] = packbf(p0,p1);
      pw32[base + (((g4>>1)    ^rsw)<<2) + 1] = packbf(p2,p3);
      pw32[base + ((((g4>>1)+2)^rsw)<<2)    ] = packbf(p4,p5);
      pw32[base + ((((g4>>1)+2)^rsw)<<2) + 1] = packbf(p6,p7);
    }
    if (lane < 16) Lcorr[wid*16 + ln] = corr;
    if (lane == 0) Lflag[wid] = wflag;
    // ---- mid-iter barrier: DS visibility only; staging DMA + V loads stay in flight
    __builtin_amdgcn_sched_barrier(0);
    asm volatile("s_waitcnt lgkmcnt(0)" ::: "memory");
    __builtin_amdgcn_s_barrier();
    __builtin_amdgcn_sched_barrier(0);
    // ---- cross-wave rescale (rare)
    {
      f32x4 fl = *(const f32x4*)&Lflag[0];
      float fs = (fl[0]+fl[1])+(fl[2]+fl[3]);
      if (fs > 0.5f){
#pragma unroll
        for (int qf=0; qf<4; ++qf){
          f32x4 c4 = *(const f32x4*)&Lcorr[qf*16 + g4*4];
#pragma unroll
          for (int df=0; df<8; ++df){
            o2[qf][df][0]*=c4[0]; o2[qf][df][1]*=c4[1];
            o2[qf][df][2]*=c4[2]; o2[qf][df][3]*=c4[3];
          }
        }
      }
    }
    // ---- PV: wave computes all 64 q for its 128-wide d-slice; V from registers
#pragma unroll
    for (int qf=0; qf<4; ++qf){
      bf16x8 aP = *(const bf16x8*)&Ps[qf*512 + ln*32 + ((g4 ^ rsw)<<3)];
#pragma unroll
      for (int df=0; df<8; ++df)
        o2[qf][df] = __builtin_amdgcn_mfma_f32_16x16x32_bf16(aP, vf[df], o2[qf][df], 0,0,0);
    }
    __syncthreads();   // drains vmcnt(0): K(kt+1) landed; all reads of cur done
  }
#undef STAGE_K
  if (lane < 16) Linv[wid*16 + ln] = 1.0f/lrun;
  __syncthreads();
  int qr0 = qt*64;
#pragma unroll
  for (int qf=0; qf<4; ++qf){
    f32x4 il4 = *(const f32x4*)&Linv[qf*16 + g4*4];
#pragma unroll
    for (int df=0; df<8; ++df){
#pragma unroll
      for (int r=0; r<4; ++r){
        int q = qr0 + qf*16 + g4*4 + r;
        int d = nh*DHn + wid*128 + df*16 + ln;
        ctx[((size_t)(b*Sn + q))*Hn + d] = f2bf(o2[qf][df][r]*il4[r]);
      }
    }
  }
}

// ---------------- LN2 in-place on f32 ----------------
__global__ __launch_bounds__(256) void ln2_kernel(float* __restrict__ t, const float* __restrict__ g,
    const float* __restrict__ be){
  __shared__ float red[4];
  int row = blockIdx.x, tid = threadIdx.x;
  const float4 x = *(const float4*)&t[(size_t)row*Hn + tid*4];
  float s = block_sum256(x.x+x.y+x.z+x.w, red);
  float mean = s*(1.0f/Hn);
  float d0=x.x-mean, d1=x.y-mean, d2=x.z-mean, d3=x.w-mean;
  float sq = block_sum256(d0*d0+d1*d1+d2*d2+d3*d3, red);
  float rstd = rsqrtf(sq*(1.0f/Hn) + 1e-12f);
  int c = tid*4;
  float4 y;
  y.x = d0*rstd*g[c+0] + be[c+0];
  y.y = d1*rstd*g[c+1] + be[c+1];
  y.z = d2*rstd*g[c+2] + be[c+2];
  y.w = d3*rstd*g[c+3] + be[c+3];
  *(float4*)&t[(size_t)row*Hn + c] = y;
}

// ---------------- span mean ----------------
__global__ __launch_bounds__(256) void span_kernel(const float* __restrict__ y, const int* __restrict__ head,
    const int* __restrict__ tail, float* __restrict__ out){
  int bs = blockIdx.x;
  int b = bs >> 5;
  int hd = head[bs], tl = tail[bs];
  int c = threadIdx.x*4;
  float a0=0.f,a1=0.f,a2=0.f,a3=0.f;
  for (int s=hd; s<tl; ++s){
    const float4 v = *(const float4*)&y[((size_t)(b*Sn + s))*Hn + c];
    a0+=v.x; a1+=v.y; a2+=v.z; a3+=v.w;
  }
  float inv = 1.0f/(float)(tl-hd);
  float4 o; o.x=a0*inv; o.y=a1*inv; o.z=a2*inv; o.w=a3*inv;
  *(float4*)&out[(size_t)bs*Hn + c] = o;
}

extern "C" void kernel_launch(void* const* d_in, const int* in_sizes, int n_in,
                              void* d_out, int out_size, void* d_ws, size_t ws_size,
                              hipStream_t stream) {
  const float* hs    = (const float*)d_in[0];
  const int*   mask  = (const int*)d_in[1];
  const int*   shead = (const int*)d_in[2];
  const int*   stail = (const int*)d_in[3];
  const float* lw    = (const float*)d_in[4];
  const float* ln1g  = (const float*)d_in[5];
  const float* ln1b  = (const float*)d_in[6];
  const float* Wq    = (const float*)d_in[7];
  const float* bq    = (const float*)d_in[8];
  const float* Wk    = (const float*)d_in[9];
  const float* bk    = (const float*)d_in[10];
  const float* Wv    = (const float*)d_in[11];
  const float* bv    = (const float*)d_in[12];
  const float* Wo    = (const float*)d_in[13];
  const float* bo    = (const float*)d_in[14];
  const float* ln2g  = (const float*)d_in[15];
  const float* ln2b  = (const float*)d_in[16];

  char* ws = (char*)d_ws;
  u16* xb  = (u16*)(ws);                 // 32 MiB
  u16* wb  = (u16*)(ws + 33554432);      // 8 MiB (Wq,Wk,Wv,Wo bf16)
  u16* qb  = (u16*)(ws + 41943040);      // 32 MiB
  u16* kb  = (u16*)(ws + 75497472);      // 32 MiB
  u16* vt  = (u16*)(ws + 109051904);     // 32 MiB
  u16* ctx = (u16*)(ws + 142606336);     // 32 MiB ; ends at 176160768
  float* t = (float*)(ws + 41943040);    // 64 MiB f32, overlays qb+kb (dead after attn)
  float* out = (float*)d_out;

  convw_kernel<<<dim3(1024,4),256,0,stream>>>(Wq,Wk,Wv,Wo,wb);
  mixln_kernel<<<Mn,256,0,stream>>>(hs,lw,ln1g,ln1b,xb);
  gemm256_kernel<0><<<256,512,0,stream>>>(xb, wb,           bq, nullptr, qb, 0.044194173824159223f);
  gemm256_kernel<0><<<256,512,0,stream>>>(xb, wb+1048576,   bk, nullptr, kb, 1.0f);
  gemm256_kernel<1><<<256,512,0,stream>>>(xb, wb+2097152,   bv, nullptr, vt, 1.0f);
  attn_kernel<<<512,256,0,stream>>>(qb,kb,vt,mask,ctx);
  gemm256_kernel<2><<<256,512,0,stream>>>(ctx, wb+3145728,  bo, xb, t, 1.0f);
  ln2_kernel<<<Mn,256,0,stream>>>(t, ln2g, ln2b);
  span_kernel<<<Bn*NSn,256,0,stream>>>(t, shead, stail, out);
}

// Round 9
// 604.345 us; speedup vs baseline: 2.1647x; 2.1647x over previous
//
#include <hip/hip_runtime.h>
#include <stdint.h>

#define Ln 4
#define Bn 8
#define Sn 2048
#define Hn 1024
#define NHn 2
#define DHn 512
#define NSn 32
#define Mn (Bn*Sn)

typedef __attribute__((ext_vector_type(8))) short bf16x8;
typedef __attribute__((ext_vector_type(4))) float f32x4;
typedef unsigned short u16;

__device__ __forceinline__ float bf2f(u16 u){
  union { unsigned int i; float f; } c; c.i = ((unsigned int)u)<<16; return c.f;
}
__device__ __forceinline__ u16 f2bf(float f){
  union { float f; unsigned int i; } c; c.f = f;
  unsigned int r = c.i + 0x7FFFu + ((c.i>>16)&1u);
  return (u16)(r>>16);
}
__device__ __forceinline__ uint32_t packbf(float a, float b){
  return (uint32_t)f2bf(a) | ((uint32_t)f2bf(b)<<16);
}
__device__ __forceinline__ void gl2lds16(const void* g, void* l){
  __builtin_amdgcn_global_load_lds((const __attribute__((address_space(1))) void*)g,
                                   (__attribute__((address_space(3))) void*)l, 16, 0, 0);
}

__device__ __forceinline__ float block_sum256(float v, float* red){
#pragma unroll
  for (int m=32;m>=1;m>>=1) v += __shfl_xor(v, m, 64);
  int tid = threadIdx.x;
  if ((tid&63)==0) red[tid>>6] = v;
  __syncthreads();
  v = red[0]+red[1]+red[2]+red[3];
  __syncthreads();
  return v;
}

// ---------------- weight f32 -> bf16 ----------------
__global__ __launch_bounds__(256) void convw_kernel(const float* __restrict__ Wq, const float* __restrict__ Wk,
    const float* __restrict__ Wv, const float* __restrict__ Wo, u16* __restrict__ wb){
  int m = blockIdx.y;
  const float* src = (m==0)?Wq:(m==1)?Wk:(m==2)?Wv:Wo;
  size_t i = ((size_t)blockIdx.x*256 + threadIdx.x)*4;
  const float4 v = *(const float4*)&src[i];
  ushort4 o;
  o.x=f2bf(v.x); o.y=f2bf(v.y); o.z=f2bf(v.z); o.w=f2bf(v.w);
  *(ushort4*)&wb[(size_t)m*Hn*Hn + i] = o;
}

// ---------------- layer mix + LN1 -> x (bf16) ----------------
__global__ __launch_bounds__(256) void mixln_kernel(const float* __restrict__ hs, const float* __restrict__ lw,
    const float* __restrict__ g, const float* __restrict__ be, u16* __restrict__ xb){
  __shared__ float red[4];
  int row = blockIdx.x;
  int tid = threadIdx.x;
  float l0=lw[0], l1=lw[1], l2=lw[2], l3=lw[3];
  float mx = fmaxf(fmaxf(l0,l1),fmaxf(l2,l3));
  float e0=__expf(l0-mx), e1=__expf(l1-mx), e2=__expf(l2-mx), e3=__expf(l3-mx);
  float inv = 1.0f/(e0+e1+e2+e3);
  e0*=inv; e1*=inv; e2*=inv; e3*=inv;
  size_t base = (size_t)row*Hn + tid*4;
  const float4 h0 = *(const float4*)&hs[base];
  const float4 h1 = *(const float4*)&hs[base + (size_t)Mn*Hn];
  const float4 h2 = *(const float4*)&hs[base + (size_t)2*Mn*Hn];
  const float4 h3 = *(const float4*)&hs[base + (size_t)3*Mn*Hn];
  float x0 = e0*h0.x + e1*h1.x + e2*h2.x + e3*h3.x;
  float x1 = e0*h0.y + e1*h1.y + e2*h2.y + e3*h3.y;
  float x2 = e0*h0.z + e1*h1.z + e2*h2.z + e3*h3.z;
  float x3 = e0*h0.w + e1*h1.w + e2*h2.w + e3*h3.w;
  float s = block_sum256(x0+x1+x2+x3, red);
  float mean = s * (1.0f/Hn);
  float d0=x0-mean, d1=x1-mean, d2=x2-mean, d3=x3-mean;
  float sq = block_sum256(d0*d0+d1*d1+d2*d2+d3*d3, red);
  float rstd = rsqrtf(sq*(1.0f/Hn) + 1e-7f);
  int c = tid*4;
  ushort4 o;
  o.x = f2bf(d0*rstd*g[c+0] + be[c+0]);
  o.y = f2bf(d1*rstd*g[c+1] + be[c+1]);
  o.z = f2bf(d2*rstd*g[c+2] + be[c+2]);
  o.w = f2bf(d3*rstd*g[c+3] + be[c+3]);
  *(ushort4*)&xb[(size_t)row*Hn + c] = o;
}

// ---------------- GEMM 256x256 tile, BK=32, triple-buffer, counted vmcnt ----------------
// C[i,j] = sum_k A[i,k]*Bw[j,k] + bias[j]. Prefetch distance 2: stage tile t+2
// while computing t; end-of-iter waits vmcnt(4) (t+2's 4 loads stay IN FLIGHT
// across the barrier; t+1's, issued a full iter ago, proven complete). Each
// wave waits its own counted vmcnt BEFORE s_barrier => all waves' older DMAs
// complete after it (m201 pattern). 16B-granule XOR swizzle (c^(row&3)),
// source pre-swizzled / dest linear (rule 21), read XORed identically.
template<int MODE>
__global__ __launch_bounds__(512,2) void gemm256_kernel(const u16* __restrict__ A, const u16* __restrict__ Bw,
    const float* __restrict__ bias, const u16* __restrict__ resid, void* __restrict__ Cout, float scale){
  __shared__ u16 Asb[3][256*32];   // 3 x 16KB
  __shared__ u16 Bsb[3][256*32];   // 3 x 16KB  (total 96KB)
  int tid = threadIdx.x, lane = tid&63, wid = tid>>6;
  int ln = lane&15, g4 = lane>>4;
  int wm = wid>>2, wn = wid&3;        // wave grid 2M x 4N; per-wave out 128x64
  int swz = (blockIdx.x&7)*32 + (blockIdx.x>>3);
  int i0 = (swz>>2)*256;
  int j0 = (swz&3)*256;

  f32x4 acc[8][4];
#pragma unroll
  for (int a=0;a<8;a++)
#pragma unroll
    for (int b=0;b<4;b++) acc[a][b] = (f32x4){0.f,0.f,0.f,0.f};

  const u16* Asrc = A + (size_t)i0*Hn;
  const u16* Bsrc = Bw + (size_t)j0*Hn;

  // stage K-tile T (32 cols) into buffer I: 4 loads/thread (2 A + 2 B).
  // granule g (0..1023): row=g>>2, col-granule cs=(g&3)^(row&3) at source.
#define STG(T,I) do { \
  _Pragma("unroll") \
  for (int c_=0;c_<2;++c_){ \
    int g_ = tid + c_*512; int r_ = g_>>2; int cs_ = (g_&3) ^ (r_&3); \
    gl2lds16(Asrc + (size_t)r_*Hn + (T)*32 + cs_*8, (char*)Asb[I] + g_*16); \
    gl2lds16(Bsrc + (size_t)r_*Hn + (T)*32 + cs_*8, (char*)Bsb[I] + g_*16); \
  } } while(0)

#define RDA(I,ROW) (*(const bf16x8*)((char*)Asb[I] + (ROW)*64 + ((g4 ^ ((ROW)&3))<<4)))
#define RDB(I,ROW) (*(const bf16x8*)((char*)Bsb[I] + (ROW)*64 + ((g4 ^ ((ROW)&3))<<4)))

  STG(0,0);
  STG(1,1);
  asm volatile("s_waitcnt vmcnt(4)" ::: "memory");   // tile 0 landed; tile 1 in flight
  __builtin_amdgcn_s_barrier();
  __builtin_amdgcn_sched_barrier(0);

#pragma unroll 1
  for (int t=0; t<32; ++t){
    int cur = t%3;
    if (t < 30) STG(t+2, (t+2)%3);
    bf16x8 af[8], bf[4];
#pragma unroll
    for (int mt=0; mt<8; ++mt) af[mt] = RDA(cur, wm*128 + mt*16 + ln);
#pragma unroll
    for (int nt=0; nt<4; ++nt) bf[nt] = RDB(cur, wn*64 + nt*16 + ln);
    asm volatile("s_waitcnt lgkmcnt(0)" ::: "memory");
    __builtin_amdgcn_sched_barrier(0);
    __builtin_amdgcn_s_setprio(1);
#pragma unroll
    for (int mt=0; mt<8; ++mt)
#pragma unroll
      for (int nt=0; nt<4; ++nt)
        acc[mt][nt] = __builtin_amdgcn_mfma_f32_16x16x32_bf16(af[mt], bf[nt], acc[mt][nt], 0,0,0);
    __builtin_amdgcn_s_setprio(0);
    if (t < 31){
      if (t < 30) asm volatile("s_waitcnt vmcnt(4)" ::: "memory");  // t+1 done; t+2 stays in flight
      else        asm volatile("s_waitcnt vmcnt(0)" ::: "memory");  // drain for final tile
      __builtin_amdgcn_s_barrier();
      __builtin_amdgcn_sched_barrier(0);
    }
  }
#undef STG
#undef RDA
#undef RDB

#pragma unroll
  for (int mt=0; mt<8; ++mt){
#pragma unroll
    for (int nt=0; nt<4; ++nt){
#pragma unroll
      for (int r=0; r<4; ++r){
        int i = i0 + wm*128 + mt*16 + g4*4 + r;
        int j = j0 + wn*64 + nt*16 + ln;
        float v = acc[mt][nt][r] + bias[j];
        if (MODE==0){
          int b = i>>11, s = i&2047, nh = j>>9, dh = j&511;
          ((u16*)Cout)[(((size_t)(b*NHn+nh)*Sn + s)<<9) + dh] = f2bf(v*scale);
        } else if (MODE==1){
          int b = i>>11, s = i&2047, nh = j>>9, dh = j&511;
          ((u16*)Cout)[((size_t)((b*NHn+nh)*(Sn/32) + (s>>5))<<14) + (dh<<5) + (s&31)] = f2bf(v);
        } else {
          float res = bf2f(resid[(size_t)i*Hn + j]);
          ((float*)Cout)[(size_t)i*Hn + j] = v + res;
        }
      }
    }
  }
}

// ---------------- flash attention (R7 structure — best measured: 228us) ----------------
// d-split PV with block-shared P: 8 waves; each wave owns 16 q-rows for
// QK/softmax and a 64-wide d-slice for PV over ALL 128 q. K+V double-buffered
// LDS, V granule-swizzled; ONE mid-iter lgkm-only barrier + end syncthreads.
__global__ __launch_bounds__(512,2) void attn_kernel(const u16* __restrict__ qb, const u16* __restrict__ kb,
    const u16* __restrict__ vt, const int* __restrict__ mask, u16* __restrict__ ctx){
  __shared__ u16 Ks[2][32*512];  // 2x32KB, row-swizzled
  __shared__ u16 Vs[2][512*32];  // 2x32KB, tiled V^T (d, k%32), granule-swizzled
  __shared__ u16 Ps[8*16*32];    // block-shared P[128q][32k], wave-region + granule-swizzled
  __shared__ float Lcorr[128];   // per-q rescale factor (1.0 if none)
  __shared__ float Lflag[8];     // per-wave rescale flag
  __shared__ float Linv[128];    // per-q 1/l (epilogue)
  int tid = threadIdx.x, lane = tid&63, wid = tid>>6;
  int ln = lane&15, g4 = lane>>4;
  int gid = blockIdx.x;
  int xcd = gid&7, ord = gid>>3;
  int bh = xcd*2 + (ord>>4), qt = ord&15;   // 16 qt-blocks of one bh share an XCD
  int b = bh >> 1, nh = bh & 1;
  u16* pw = Ps + wid*512;
  uint32_t* pw32 = (uint32_t*)pw;
  const int swz = (ln&7)<<4;
  const int rsw = (ln>>1)&3;     // P/V swizzle key

  bf16x8 aq[16];
  size_t qoff = ((size_t)bh*Sn + qt*128 + wid*16 + ln)*DHn + g4*8;
#pragma unroll
  for (int ch=0; ch<16; ++ch) aq[ch] = *(const bf16x8*)&qb[qoff + ch*32];

  // o2[qf][df]: q = qf*16 + g4*4 + r ; d = wid*64 + df*16 + ln
  f32x4 o2[8][4];
#pragma unroll
  for (int qf=0; qf<8; ++qf)
#pragma unroll
    for (int df=0; df<4; ++df) o2[qf][df] = (f32x4){0.f,0.f,0.f,0.f};
  float mrun = -1e30f, lrun = 0.f;

  const size_t kbase = (size_t)bh*Sn*DHn;
  const u16* vtile = vt + (size_t)bh*Sn*DHn;   // tiled V^T: [kt][512 d][32 k]

#define STAGE_KV(KT,BUF) do { \
  _Pragma("unroll") \
  for (int t_=0; t_<4; ++t_){ \
    int krow_ = t_*8 + wid; \
    int koff_ = (lane*16) ^ ((krow_&7)<<4); \
    gl2lds16(&kb[kbase + ((size_t)((KT)*32 + krow_))*DHn + (koff_>>1)], \
             (char*)Ks[BUF] + krow_*1024 + lane*16); \
  } \
  _Pragma("unroll") \
  for (int t_=0; t_<4; ++t_){ \
    int p_ = t_*512 + tid; \
    int cgd_ = ((p_&3) ^ ((p_>>3)&3)); \
    gl2lds16(&vtile[(size_t)(KT)*16384 + (p_&~3)*8 + cgd_*8], \
             (char*)Vs[BUF] + p_*16); \
  } } while(0)

  STAGE_KV(0,0);
  __syncthreads();   // tile 0 resident
#pragma unroll 1
  for (int kt=0; kt<Sn/32; ++kt){
    int cur = kt&1;
    if (kt < Sn/32 - 1) STAGE_KV(kt+1, cur^1);   // DMA spans the raw barrier; drained at end sync
    const char* KsB = (const char*)Ks[cur];
    f32x4 s0 = (f32x4){0.f,0.f,0.f,0.f};
    f32x4 s1 = (f32x4){0.f,0.f,0.f,0.f};
#pragma unroll
    for (int ch=0; ch<16; ++ch){
      bf16x8 k0 = *(const bf16x8*)(KsB + ln*1024      + ((ch*64 + g4*16) ^ swz));
      bf16x8 k1 = *(const bf16x8*)(KsB + (16+ln)*1024 + ((ch*64 + g4*16) ^ swz));
      s0 = __builtin_amdgcn_mfma_f32_16x16x32_bf16(k0, aq[ch], s0, 0,0,0);
      s1 = __builtin_amdgcn_mfma_f32_16x16x32_bf16(k1, aq[ch], s1, 0,0,0);
    }
    int4 mk0 = *(const int4*)&mask[b*Sn + kt*32 + g4*4];
    int4 mk1 = *(const int4*)&mask[b*Sn + kt*32 + 16 + g4*4];
    s0[0] += (float)(1-mk0.x)*-10000.0f; s0[1] += (float)(1-mk0.y)*-10000.0f;
    s0[2] += (float)(1-mk0.z)*-10000.0f; s0[3] += (float)(1-mk0.w)*-10000.0f;
    s1[0] += (float)(1-mk1.x)*-10000.0f; s1[1] += (float)(1-mk1.y)*-10000.0f;
    s1[2] += (float)(1-mk1.z)*-10000.0f; s1[3] += (float)(1-mk1.w)*-10000.0f;
    float tmax = fmaxf(fmaxf(fmaxf(s0[0],s0[1]),fmaxf(s0[2],s0[3])),
                       fmaxf(fmaxf(s1[0],s1[1]),fmaxf(s1[2],s1[3])));
    tmax = fmaxf(tmax, __shfl_xor(tmax, 16));
    tmax = fmaxf(tmax, __shfl_xor(tmax, 32));
    float corr = 1.0f, wflag = 0.0f;
    if (__any(tmax > mrun + 8.0f)){     // defer-max: rare rescale
      float nm = fmaxf(mrun, tmax);
      corr = __expf(mrun - nm);
      mrun = nm; lrun *= corr;
      wflag = 1.0f;
    }
    float p0=__expf(s0[0]-mrun), p1=__expf(s0[1]-mrun), p2=__expf(s0[2]-mrun), p3=__expf(s0[3]-mrun);
    float p4=__expf(s1[0]-mrun), p5=__expf(s1[1]-mrun), p6=__expf(s1[2]-mrun), p7=__expf(s1[3]-mrun);
    float sum = ((p0+p1)+(p2+p3)) + ((p4+p5)+(p6+p7));
    sum += __shfl_xor(sum, 16);
    sum += __shfl_xor(sum, 32);
    lrun += sum;
    // P write: swizzled granules — granule (q,gr) at u16 q*32 + (gr^((q>>1)&3))*8.
    {
      int base = ln*16 + ((g4&1)<<1);
      pw32[base + (((g4>>1)    ^rsw)<<2)    ] = packbf(p0,p1);
      pw32[base + (((g4>>1)    ^rsw)<<2) + 1] = packbf(p2,p3);
      pw32[base + ((((g4>>1)+2)^rsw)<<2)    ] = packbf(p4,p5);
      pw32[base + ((((g4>>1)+2)^rsw)<<2) + 1] = packbf(p6,p7);
    }
    if (lane < 16) Lcorr[wid*16 + ln] = corr;
    if (lane == 0) Lflag[wid] = wflag;
    // ---- mid-iter barrier: DS visibility only; staging DMA stays in flight
    __builtin_amdgcn_sched_barrier(0);
    asm volatile("s_waitcnt lgkmcnt(0)" ::: "memory");
    __builtin_amdgcn_s_barrier();
    __builtin_amdgcn_sched_barrier(0);
    // ---- cross-wave rescale (rare)
    {
      f32x4 fl0 = *(const f32x4*)&Lflag[0];
      f32x4 fl1 = *(const f32x4*)&Lflag[4];
      float fs = (fl0[0]+fl0[1]+fl0[2]+fl0[3]) + (fl1[0]+fl1[1]+fl1[2]+fl1[3]);
      if (fs > 0.5f){
#pragma unroll
        for (int qf=0; qf<8; ++qf){
          f32x4 c4 = *(const f32x4*)&Lcorr[qf*16 + g4*4];
#pragma unroll
          for (int df=0; df<4; ++df){
            o2[qf][df][0]*=c4[0]; o2[qf][df][1]*=c4[1];
            o2[qf][df][2]*=c4[2]; o2[qf][df][3]*=c4[3];
          }
        }
      }
    }
    // ---- PV: wave computes all 128 q for its 64-wide d-slice
    const char* VsB = (const char*)Vs[cur];
    bf16x8 bv[4];
#pragma unroll
    for (int df=0; df<4; ++df)
      bv[df] = *(const bf16x8*)(VsB + ((wid*4+df)*16+ln)*64 + ((g4 ^ rsw)<<4));
#pragma unroll
    for (int qf=0; qf<8; ++qf){
      bf16x8 aP = *(const bf16x8*)&Ps[qf*512 + ln*32 + ((g4 ^ rsw)<<3)];
#pragma unroll
      for (int df=0; df<4; ++df)
        o2[qf][df] = __builtin_amdgcn_mfma_f32_16x16x32_bf16(aP, bv[df], o2[qf][df], 0,0,0);
    }
    __syncthreads();   // drains vmcnt(0): tile kt+1 landed; all reads of cur done
  }
#undef STAGE_KV
  if (lane < 16) Linv[wid*16 + ln] = 1.0f/lrun;
  __syncthreads();
  int qr0 = qt*128;
#pragma unroll
  for (int qf=0; qf<8; ++qf){
    f32x4 il4 = *(const f32x4*)&Linv[qf*16 + g4*4];
#pragma unroll
    for (int df=0; df<4; ++df){
#pragma unroll
      for (int r=0; r<4; ++r){
        int q = qr0 + qf*16 + g4*4 + r;
        int d = nh*DHn + wid*64 + df*16 + ln;
        ctx[((size_t)(b*Sn + q))*Hn + d] = f2bf(o2[qf][df][r]*il4[r]);
      }
    }
  }
}

// ---------------- LN2 in-place on f32 ----------------
__global__ __launch_bounds__(256) void ln2_kernel(float* __restrict__ t, const float* __restrict__ g,
    const float* __restrict__ be){
  __shared__ float red[4];
  int row = blockIdx.x, tid = threadIdx.x;
  const float4 x = *(const float4*)&t[(size_t)row*Hn + tid*4];
  float s = block_sum256(x.x+x.y+x.z+x.w, red);
  float mean = s*(1.0f/Hn);
  float d0=x.x-mean, d1=x.y-mean, d2=x.z-mean, d3=x.w-mean;
  float sq = block_sum256(d0*d0+d1*d1+d2*d2+d3*d3, red);
  float rstd = rsqrtf(sq*(1.0f/Hn) + 1e-12f);
  int c = tid*4;
  float4 y;
  y.x = d0*rstd*g[c+0] + be[c+0];
  y.y = d1*rstd*g[c+1] + be[c+1];
  y.z = d2*rstd*g[c+2] + be[c+2];
  y.w = d3*rstd*g[c+3] + be[c+3];
  *(float4*)&t[(size_t)row*Hn + c] = y;
}

// ---------------- span mean ----------------
__global__ __launch_bounds__(256) void span_kernel(const float* __restrict__ y, const int* __restrict__ head,
    const int* __restrict__ tail, float* __restrict__ out){
  int bs = blockIdx.x;
  int b = bs >> 5;
  int hd = head[bs], tl = tail[bs];
  int c = threadIdx.x*4;
  float a0=0.f,a1=0.f,a2=0.f,a3=0.f;
  for (int s=hd; s<tl; ++s){
    const float4 v = *(const float4*)&y[((size_t)(b*Sn + s))*Hn + c];
    a0+=v.x; a1+=v.y; a2+=v.z; a3+=v.w;
  }
  float inv = 1.0f/(float)(tl-hd);
  float4 o; o.x=a0*inv; o.y=a1*inv; o.z=a2*inv; o.w=a3*inv;
  *(float4*)&out[(size_t)bs*Hn + c] = o;
}

extern "C" void kernel_launch(void* const* d_in, const int* in_sizes, int n_in,
                              void* d_out, int out_size, void* d_ws, size_t ws_size,
                              hipStream_t stream) {
  const float* hs    = (const float*)d_in[0];
  const int*   mask  = (const int*)d_in[1];
  const int*   shead = (const int*)d_in[2];
  const int*   stail = (const int*)d_in[3];
  const float* lw    = (const float*)d_in[4];
  const float* ln1g  = (const float*)d_in[5];
  const float* ln1b  = (const float*)d_in[6];
  const float* Wq    = (const float*)d_in[7];
  const float* bq    = (const float*)d_in[8];
  const float* Wk    = (const float*)d_in[9];
  const float* bk    = (const float*)d_in[10];
  const float* Wv    = (const float*)d_in[11];
  const float* bv    = (const float*)d_in[12];
  const float* Wo    = (const float*)d_in[13];
  const float* bo    = (const float*)d_in[14];
  const float* ln2g  = (const float*)d_in[15];
  const float* ln2b  = (const float*)d_in[16];

  char* ws = (char*)d_ws;
  u16* xb  = (u16*)(ws);                 // 32 MiB
  u16* wb  = (u16*)(ws + 33554432);      // 8 MiB (Wq,Wk,Wv,Wo bf16)
  u16* qb  = (u16*)(ws + 41943040);      // 32 MiB
  u16* kb  = (u16*)(ws + 75497472);      // 32 MiB
  u16* vt  = (u16*)(ws + 109051904);     // 32 MiB
  u16* ctx = (u16*)(ws + 142606336);     // 32 MiB ; ends at 176160768
  float* t = (float*)(ws + 41943040);    // 64 MiB f32, overlays qb+kb (dead after attn)
  float* out = (float*)d_out;

  convw_kernel<<<dim3(1024,4),256,0,stream>>>(Wq,Wk,Wv,Wo,wb);
  mixln_kernel<<<Mn,256,0,stream>>>(hs,lw,ln1g,ln1b,xb);
  gemm256_kernel<0><<<256,512,0,stream>>>(xb, wb,           bq, nullptr, qb, 0.044194173824159223f);
  gemm256_kernel<0><<<256,512,0,stream>>>(xb, wb+1048576,   bk, nullptr, kb, 1.0f);
  gemm256_kernel<1><<<256,512,0,stream>>>(xb, wb+2097152,   bv, nullptr, vt, 1.0f);
  attn_kernel<<<256,512,0,stream>>>(qb,kb,vt,mask,ctx);
  gemm256_kernel<2><<<256,512,0,stream>>>(ctx, wb+3145728,  bo, xb, t, 1.0f);
  ln2_kernel<<<Mn,256,0,stream>>>(t, ln2g, ln2b);
  span_kernel<<<Bn*NSn,256,0,stream>>>(t, shead, stail, out);
}

// Round 10
// 547.379 us; speedup vs baseline: 2.3899x; 1.1041x over previous
//
#include <hip/hip_runtime.h>
#include <stdint.h>

#define Ln 4
#define Bn 8
#define Sn 2048
#define Hn 1024
#define NHn 2
#define DHn 512
#define NSn 32
#define Mn (Bn*Sn)

typedef __attribute__((ext_vector_type(8))) short bf16x8;
typedef __attribute__((ext_vector_type(4))) float f32x4;
typedef unsigned short u16;

__device__ __forceinline__ float bf2f(u16 u){
  union { unsigned int i; float f; } c; c.i = ((unsigned int)u)<<16; return c.f;
}
__device__ __forceinline__ u16 f2bf(float f){
  union { float f; unsigned int i; } c; c.f = f;
  unsigned int r = c.i + 0x7FFFu + ((c.i>>16)&1u);
  return (u16)(r>>16);
}
__device__ __forceinline__ uint32_t packbf(float a, float b){
  return (uint32_t)f2bf(a) | ((uint32_t)f2bf(b)<<16);
}
__device__ __forceinline__ void gl2lds16(const void* g, void* l){
  __builtin_amdgcn_global_load_lds((const __attribute__((address_space(1))) void*)g,
                                   (__attribute__((address_space(3))) void*)l, 16, 0, 0);
}

__device__ __forceinline__ float block_sum256(float v, float* red){
#pragma unroll
  for (int m=32;m>=1;m>>=1) v += __shfl_xor(v, m, 64);
  int tid = threadIdx.x;
  if ((tid&63)==0) red[tid>>6] = v;
  __syncthreads();
  v = red[0]+red[1]+red[2]+red[3];
  __syncthreads();
  return v;
}

// ---------------- weight f32 -> bf16 ----------------
__global__ __launch_bounds__(256) void convw_kernel(const float* __restrict__ Wq, const float* __restrict__ Wk,
    const float* __restrict__ Wv, const float* __restrict__ Wo, u16* __restrict__ wb){
  int m = blockIdx.y;
  const float* src = (m==0)?Wq:(m==1)?Wk:(m==2)?Wv:Wo;
  size_t i = ((size_t)blockIdx.x*256 + threadIdx.x)*4;
  const float4 v = *(const float4*)&src[i];
  ushort4 o;
  o.x=f2bf(v.x); o.y=f2bf(v.y); o.z=f2bf(v.z); o.w=f2bf(v.w);
  *(ushort4*)&wb[(size_t)m*Hn*Hn + i] = o;
}

// ---------------- layer mix + LN1 -> x (bf16) ----------------
__global__ __launch_bounds__(256) void mixln_kernel(const float* __restrict__ hs, const float* __restrict__ lw,
    const float* __restrict__ g, const float* __restrict__ be, u16* __restrict__ xb){
  __shared__ float red[4];
  int row = blockIdx.x;
  int tid = threadIdx.x;
  float l0=lw[0], l1=lw[1], l2=lw[2], l3=lw[3];
  float mx = fmaxf(fmaxf(l0,l1),fmaxf(l2,l3));
  float e0=__expf(l0-mx), e1=__expf(l1-mx), e2=__expf(l2-mx), e3=__expf(l3-mx);
  float inv = 1.0f/(e0+e1+e2+e3);
  e0*=inv; e1*=inv; e2*=inv; e3*=inv;
  size_t base = (size_t)row*Hn + tid*4;
  const float4 h0 = *(const float4*)&hs[base];
  const float4 h1 = *(const float4*)&hs[base + (size_t)Mn*Hn];
  const float4 h2 = *(const float4*)&hs[base + (size_t)2*Mn*Hn];
  const float4 h3 = *(const float4*)&hs[base + (size_t)3*Mn*Hn];
  float x0 = e0*h0.x + e1*h1.x + e2*h2.x + e3*h3.x;
  float x1 = e0*h0.y + e1*h1.y + e2*h2.y + e3*h3.y;
  float x2 = e0*h0.z + e1*h1.z + e2*h2.z + e3*h3.z;
  float x3 = e0*h0.w + e1*h1.w + e2*h2.w + e3*h3.w;
  float s = block_sum256(x0+x1+x2+x3, red);
  float mean = s * (1.0f/Hn);
  float d0=x0-mean, d1=x1-mean, d2=x2-mean, d3=x3-mean;
  float sq = block_sum256(d0*d0+d1*d1+d2*d2+d3*d3, red);
  float rstd = rsqrtf(sq*(1.0f/Hn) + 1e-7f);
  int c = tid*4;
  ushort4 o;
  o.x = f2bf(d0*rstd*g[c+0] + be[c+0]);
  o.y = f2bf(d1*rstd*g[c+1] + be[c+1]);
  o.z = f2bf(d2*rstd*g[c+2] + be[c+2]);
  o.w = f2bf(d3*rstd*g[c+3] + be[c+3]);
  *(ushort4*)&xb[(size_t)row*Hn + c] = o;
}

// ---------------- GEMM 256x256 tile, BK=64, 8 waves, phase-split (R7, proven) ----------------
// MODE 0: bf16 to (b,nh,s,dh), scaled. MODE 1: bf16 tiled V^T. MODE 2: bf16 + residual.
template<int MODE>
__global__ __launch_bounds__(512,2) void gemm256_kernel(const u16* __restrict__ A, const u16* __restrict__ Bw,
    const float* __restrict__ bias, const u16* __restrict__ resid, void* __restrict__ Cout, float scale){
  __shared__ char lds[2][2][32768];   // [buf][A/B][256 rows x 64 cols bf16]
  int tid = threadIdx.x, lane = tid&63, wid = tid>>6;
  int ln = lane&15, g4 = lane>>4;
  int wm = wid>>2, wn = wid&3;        // wave grid 2M x 4N; per-wave out 128x64
  int swz = (blockIdx.x&7)*32 + (blockIdx.x>>3);
  int i0 = (swz>>2)*256;
  int j0 = (swz&3)*256;

  f32x4 acc[8][4];
#pragma unroll
  for (int a=0;a<8;a++)
#pragma unroll
    for (int b=0;b<4;b++) acc[a][b] = (f32x4){0.f,0.f,0.f,0.f};

  const u16* Asrc = A + (size_t)i0*Hn;
  const u16* Bsrc = Bw + (size_t)j0*Hn;

#define STAGE1(SRC, DST, G) do { \
    int g_ = (G); int row_ = g_>>3; int cs_ = (g_&7) ^ (row_&7); \
    gl2lds16((SRC) + (size_t)row_*Hn + cs_*8, (DST) + g_*16); } while(0)

#define RD(BASE, ROW, KG) (*(const bf16x8*)((BASE) + (ROW)*128 + ((((KG)) ^ ((ROW)&7))<<4)))

  {
    const u16* An_ = Asrc; const u16* Bn_ = Bsrc;
#pragma unroll
    for (int c=0;c<4;++c){ STAGE1(An_, lds[0][0], tid + c*512); }
#pragma unroll
    for (int c=0;c<4;++c){ STAGE1(Bn_, lds[0][1], tid + c*512); }
  }
  __syncthreads();

  bf16x8 af[4][2], bf0[2][2], bf1[2][2];

#pragma unroll 1
  for (int t=0; t<16; ++t){
    const char* Ac = lds[t&1][0];
    const char* Bc = lds[t&1][1];
    char* Anx = lds[(t+1)&1][0];
    char* Bnx = lds[(t+1)&1][1];
    const u16* An_ = Asrc + (t+1)*64;
    const u16* Bn_ = Bsrc + (t+1)*64;
    bool st = (t < 15);
    if (st){ STAGE1(An_, Anx, tid); STAGE1(An_, Anx, tid+512); STAGE1(Bn_, Bnx, tid); }
#pragma unroll
    for (int mt=0; mt<4; ++mt)
#pragma unroll
      for (int kk=0; kk<2; ++kk) af[mt][kk] = RD(Ac, wm*128 + mt*16 + ln, kk*4+g4);
#pragma unroll
    for (int nt=0; nt<2; ++nt)
#pragma unroll
      for (int kk=0; kk<2; ++kk) bf0[nt][kk] = RD(Bc, wn*64 + nt*16 + ln, kk*4+g4);
    __builtin_amdgcn_s_barrier();
    __builtin_amdgcn_s_setprio(1);
#pragma unroll
    for (int kk=0; kk<2; ++kk)
#pragma unroll
      for (int mt=0; mt<4; ++mt)
#pragma unroll
        for (int nt=0; nt<2; ++nt)
          acc[mt][nt] = __builtin_amdgcn_mfma_f32_16x16x32_bf16(af[mt][kk], bf0[nt][kk], acc[mt][nt], 0,0,0);
    __builtin_amdgcn_s_setprio(0);
    if (st){ STAGE1(Bn_, Bnx, tid+512); STAGE1(An_, Anx, tid+1024); STAGE1(An_, Anx, tid+1536); }
#pragma unroll
    for (int nt=0; nt<2; ++nt)
#pragma unroll
      for (int kk=0; kk<2; ++kk) bf1[nt][kk] = RD(Bc, wn*64 + (2+nt)*16 + ln, kk*4+g4);
    __builtin_amdgcn_s_barrier();
    __builtin_amdgcn_s_setprio(1);
#pragma unroll
    for (int kk=0; kk<2; ++kk)
#pragma unroll
      for (int mt=0; mt<4; ++mt)
#pragma unroll
        for (int nt=0; nt<2; ++nt)
          acc[mt][2+nt] = __builtin_amdgcn_mfma_f32_16x16x32_bf16(af[mt][kk], bf1[nt][kk], acc[mt][2+nt], 0,0,0);
    __builtin_amdgcn_s_setprio(0);
    if (st){ STAGE1(Bn_, Bnx, tid+1024); STAGE1(Bn_, Bnx, tid+1536); }
#pragma unroll
    for (int mt=0; mt<4; ++mt)
#pragma unroll
      for (int kk=0; kk<2; ++kk) af[mt][kk] = RD(Ac, wm*128 + 64 + mt*16 + ln, kk*4+g4);
    __builtin_amdgcn_s_barrier();
    __builtin_amdgcn_s_setprio(1);
#pragma unroll
    for (int kk=0; kk<2; ++kk)
#pragma unroll
      for (int mt=0; mt<4; ++mt)
#pragma unroll
        for (int nt=0; nt<2; ++nt)
          acc[4+mt][nt] = __builtin_amdgcn_mfma_f32_16x16x32_bf16(af[mt][kk], bf0[nt][kk], acc[4+mt][nt], 0,0,0);
    __builtin_amdgcn_s_setprio(0);
    __builtin_amdgcn_s_barrier();
    __builtin_amdgcn_s_setprio(1);
#pragma unroll
    for (int kk=0; kk<2; ++kk)
#pragma unroll
      for (int mt=0; mt<4; ++mt)
#pragma unroll
        for (int nt=0; nt<2; ++nt)
          acc[4+mt][2+nt] = __builtin_amdgcn_mfma_f32_16x16x32_bf16(af[mt][kk], bf1[nt][kk], acc[4+mt][2+nt], 0,0,0);
    __builtin_amdgcn_s_setprio(0);
    __syncthreads();
  }
#undef STAGE1
#undef RD

#pragma unroll
  for (int mt=0; mt<8; ++mt){
#pragma unroll
    for (int nt=0; nt<4; ++nt){
#pragma unroll
      for (int r=0; r<4; ++r){
        int i = i0 + wm*128 + mt*16 + g4*4 + r;
        int j = j0 + wn*64 + nt*16 + ln;
        float v = acc[mt][nt][r] + bias[j];
        if (MODE==0){
          int b = i>>11, s = i&2047, nh = j>>9, dh = j&511;
          ((u16*)Cout)[(((size_t)(b*NHn+nh)*Sn + s)<<9) + dh] = f2bf(v*scale);
        } else if (MODE==1){
          int b = i>>11, s = i&2047, nh = j>>9, dh = j&511;
          ((u16*)Cout)[((size_t)((b*NHn+nh)*(Sn/32) + (s>>5))<<14) + (dh<<5) + (s&31)] = f2bf(v);
        } else {
          float res = bf2f(resid[(size_t)i*Hn + j]);
          ((u16*)Cout)[(size_t)i*Hn + j] = f2bf(v + res);
        }
      }
    }
  }
}

// ---------------- flash attention (R7 structure — best measured: ~227us) ----------------
__global__ __launch_bounds__(512,2) void attn_kernel(const u16* __restrict__ qb, const u16* __restrict__ kb,
    const u16* __restrict__ vt, const int* __restrict__ mask, u16* __restrict__ ctx){
  __shared__ u16 Ks[2][32*512];  // 2x32KB, row-swizzled
  __shared__ u16 Vs[2][512*32];  // 2x32KB, tiled V^T (d, k%32), granule-swizzled
  __shared__ u16 Ps[8*16*32];    // block-shared P[128q][32k], wave-region + granule-swizzled
  __shared__ float Lcorr[128];   // per-q rescale factor (1.0 if none)
  __shared__ float Lflag[8];     // per-wave rescale flag
  __shared__ float Linv[128];    // per-q 1/l (epilogue)
  int tid = threadIdx.x, lane = tid&63, wid = tid>>6;
  int ln = lane&15, g4 = lane>>4;
  int gid = blockIdx.x;
  int xcd = gid&7, ord = gid>>3;
  int bh = xcd*2 + (ord>>4), qt = ord&15;   // 16 qt-blocks of one bh share an XCD
  int b = bh >> 1, nh = bh & 1;
  u16* pw = Ps + wid*512;
  uint32_t* pw32 = (uint32_t*)pw;
  const int swz = (ln&7)<<4;
  const int rsw = (ln>>1)&3;     // P/V swizzle key

  bf16x8 aq[16];
  size_t qoff = ((size_t)bh*Sn + qt*128 + wid*16 + ln)*DHn + g4*8;
#pragma unroll
  for (int ch=0; ch<16; ++ch) aq[ch] = *(const bf16x8*)&qb[qoff + ch*32];

  // o2[qf][df]: q = qf*16 + g4*4 + r ; d = wid*64 + df*16 + ln
  f32x4 o2[8][4];
#pragma unroll
  for (int qf=0; qf<8; ++qf)
#pragma unroll
    for (int df=0; df<4; ++df) o2[qf][df] = (f32x4){0.f,0.f,0.f,0.f};
  float mrun = -1e30f, lrun = 0.f;

  const size_t kbase = (size_t)bh*Sn*DHn;
  const u16* vtile = vt + (size_t)bh*Sn*DHn;   // tiled V^T: [kt][512 d][32 k]

#define STAGE_KV(KT,BUF) do { \
  _Pragma("unroll") \
  for (int t_=0; t_<4; ++t_){ \
    int krow_ = t_*8 + wid; \
    int koff_ = (lane*16) ^ ((krow_&7)<<4); \
    gl2lds16(&kb[kbase + ((size_t)((KT)*32 + krow_))*DHn + (koff_>>1)], \
             (char*)Ks[BUF] + krow_*1024 + lane*16); \
  } \
  _Pragma("unroll") \
  for (int t_=0; t_<4; ++t_){ \
    int p_ = t_*512 + tid; \
    int cgd_ = ((p_&3) ^ ((p_>>3)&3)); \
    gl2lds16(&vtile[(size_t)(KT)*16384 + (p_&~3)*8 + cgd_*8], \
             (char*)Vs[BUF] + p_*16); \
  } } while(0)

  STAGE_KV(0,0);
  __syncthreads();   // tile 0 resident
#pragma unroll 1
  for (int kt=0; kt<Sn/32; ++kt){
    int cur = kt&1;
    if (kt < Sn/32 - 1) STAGE_KV(kt+1, cur^1);   // DMA spans the raw barrier; drained at end sync
    const char* KsB = (const char*)Ks[cur];
    f32x4 s0 = (f32x4){0.f,0.f,0.f,0.f};
    f32x4 s1 = (f32x4){0.f,0.f,0.f,0.f};
#pragma unroll
    for (int ch=0; ch<16; ++ch){
      bf16x8 k0 = *(const bf16x8*)(KsB + ln*1024      + ((ch*64 + g4*16) ^ swz));
      bf16x8 k1 = *(const bf16x8*)(KsB + (16+ln)*1024 + ((ch*64 + g4*16) ^ swz));
      s0 = __builtin_amdgcn_mfma_f32_16x16x32_bf16(k0, aq[ch], s0, 0,0,0);
      s1 = __builtin_amdgcn_mfma_f32_16x16x32_bf16(k1, aq[ch], s1, 0,0,0);
    }
    int4 mk0 = *(const int4*)&mask[b*Sn + kt*32 + g4*4];
    int4 mk1 = *(const int4*)&mask[b*Sn + kt*32 + 16 + g4*4];
    s0[0] += (float)(1-mk0.x)*-10000.0f; s0[1] += (float)(1-mk0.y)*-10000.0f;
    s0[2] += (float)(1-mk0.z)*-10000.0f; s0[3] += (float)(1-mk0.w)*-10000.0f;
    s1[0] += (float)(1-mk1.x)*-10000.0f; s1[1] += (float)(1-mk1.y)*-10000.0f;
    s1[2] += (float)(1-mk1.z)*-10000.0f; s1[3] += (float)(1-mk1.w)*-10000.0f;
    float tmax = fmaxf(fmaxf(fmaxf(s0[0],s0[1]),fmaxf(s0[2],s0[3])),
                       fmaxf(fmaxf(s1[0],s1[1]),fmaxf(s1[2],s1[3])));
    tmax = fmaxf(tmax, __shfl_xor(tmax, 16));
    tmax = fmaxf(tmax, __shfl_xor(tmax, 32));
    float corr = 1.0f, wflag = 0.0f;
    if (__any(tmax > mrun + 8.0f)){     // defer-max: rare rescale
      float nm = fmaxf(mrun, tmax);
      corr = __expf(mrun - nm);
      mrun = nm; lrun *= corr;
      wflag = 1.0f;
    }
    float p0=__expf(s0[0]-mrun), p1=__expf(s0[1]-mrun), p2=__expf(s0[2]-mrun), p3=__expf(s0[3]-mrun);
    float p4=__expf(s1[0]-mrun), p5=__expf(s1[1]-mrun), p6=__expf(s1[2]-mrun), p7=__expf(s1[3]-mrun);
    float sum = ((p0+p1)+(p2+p3)) + ((p4+p5)+(p6+p7));
    sum += __shfl_xor(sum, 16);
    sum += __shfl_xor(sum, 32);
    lrun += sum;
    // P write: swizzled granules — granule (q,gr) at u16 q*32 + (gr^((q>>1)&3))*8.
    {
      int base = ln*16 + ((g4&1)<<1);
      pw32[base + (((g4>>1)    ^rsw)<<2)    ] = packbf(p0,p1);
      pw32[base + (((g4>>1)    ^rsw)<<2) + 1] = packbf(p2,p3);
      pw32[base + ((((g4>>1)+2)^rsw)<<2)    ] = packbf(p4,p5);
      pw32[base + ((((g4>>1)+2)^rsw)<<2) + 1] = packbf(p6,p7);
    }
    if (lane < 16) Lcorr[wid*16 + ln] = corr;
    if (lane == 0) Lflag[wid] = wflag;
    // ---- mid-iter barrier: DS visibility only; staging DMA stays in flight
    __builtin_amdgcn_sched_barrier(0);
    asm volatile("s_waitcnt lgkmcnt(0)" ::: "memory");
    __builtin_amdgcn_s_barrier();
    __builtin_amdgcn_sched_barrier(0);
    // ---- cross-wave rescale (rare)
    {
      f32x4 fl0 = *(const f32x4*)&Lflag[0];
      f32x4 fl1 = *(const f32x4*)&Lflag[4];
      float fs = (fl0[0]+fl0[1]+fl0[2]+fl0[3]) + (fl1[0]+fl1[1]+fl1[2]+fl1[3]);
      if (fs > 0.5f){
#pragma unroll
        for (int qf=0; qf<8; ++qf){
          f32x4 c4 = *(const f32x4*)&Lcorr[qf*16 + g4*4];
#pragma unroll
          for (int df=0; df<4; ++df){
            o2[qf][df][0]*=c4[0]; o2[qf][df][1]*=c4[1];
            o2[qf][df][2]*=c4[2]; o2[qf][df][3]*=c4[3];
          }
        }
      }
    }
    // ---- PV: wave computes all 128 q for its 64-wide d-slice
    const char* VsB = (const char*)Vs[cur];
    bf16x8 bv[4];
#pragma unroll
    for (int df=0; df<4; ++df)
      bv[df] = *(const bf16x8*)(VsB + ((wid*4+df)*16+ln)*64 + ((g4 ^ rsw)<<4));
#pragma unroll
    for (int qf=0; qf<8; ++qf){
      bf16x8 aP = *(const bf16x8*)&Ps[qf*512 + ln*32 + ((g4 ^ rsw)<<3)];
#pragma unroll
      for (int df=0; df<4; ++df)
        o2[qf][df] = __builtin_amdgcn_mfma_f32_16x16x32_bf16(aP, bv[df], o2[qf][df], 0,0,0);
    }
    __syncthreads();   // drains vmcnt(0): tile kt+1 landed; all reads of cur done
  }
#undef STAGE_KV
  if (lane < 16) Linv[wid*16 + ln] = 1.0f/lrun;
  __syncthreads();
  int qr0 = qt*128;
#pragma unroll
  for (int qf=0; qf<8; ++qf){
    f32x4 il4 = *(const f32x4*)&Linv[qf*16 + g4*4];
#pragma unroll
    for (int df=0; df<4; ++df){
#pragma unroll
      for (int r=0; r<4; ++r){
        int q = qr0 + qf*16 + g4*4 + r;
        int d = nh*DHn + wid*64 + df*16 + ln;
        ctx[((size_t)(b*Sn + q))*Hn + d] = f2bf(o2[qf][df][r]*il4[r]);
      }
    }
  }
}

// ---------------- LN2 in-place on bf16 ----------------
__global__ __launch_bounds__(256) void ln2_kernel(u16* __restrict__ t, const float* __restrict__ g,
    const float* __restrict__ be){
  __shared__ float red[4];
  int row = blockIdx.x, tid = threadIdx.x;
  const ushort4 xu = *(const ushort4*)&t[(size_t)row*Hn + tid*4];
  float x0 = bf2f(xu.x), x1 = bf2f(xu.y), x2 = bf2f(xu.z), x3 = bf2f(xu.w);
  float s = block_sum256(x0+x1+x2+x3, red);
  float mean = s*(1.0f/Hn);
  float d0=x0-mean, d1=x1-mean, d2=x2-mean, d3=x3-mean;
  float sq = block_sum256(d0*d0+d1*d1+d2*d2+d3*d3, red);
  float rstd = rsqrtf(sq*(1.0f/Hn) + 1e-12f);
  int c = tid*4;
  ushort4 y;
  y.x = f2bf(d0*rstd*g[c+0] + be[c+0]);
  y.y = f2bf(d1*rstd*g[c+1] + be[c+1]);
  y.z = f2bf(d2*rstd*g[c+2] + be[c+2]);
  y.w = f2bf(d3*rstd*g[c+3] + be[c+3]);
  *(ushort4*)&t[(size_t)row*Hn + c] = y;
}

// ---------------- span mean (bf16 input) ----------------
__global__ __launch_bounds__(256) void span_kernel(const u16* __restrict__ y, const int* __restrict__ head,
    const int* __restrict__ tail, float* __restrict__ out){
  int bs = blockIdx.x;
  int b = bs >> 5;
  int hd = head[bs], tl = tail[bs];
  int c = threadIdx.x*4;
  float a0=0.f,a1=0.f,a2=0.f,a3=0.f;
  for (int s=hd; s<tl; ++s){
    const ushort4 v = *(const ushort4*)&y[((size_t)(b*Sn + s))*Hn + c];
    a0+=bf2f(v.x); a1+=bf2f(v.y); a2+=bf2f(v.z); a3+=bf2f(v.w);
  }
  float inv = 1.0f/(float)(tl-hd);
  float4 o; o.x=a0*inv; o.y=a1*inv; o.z=a2*inv; o.w=a3*inv;
  *(float4*)&out[(size_t)bs*Hn + c] = o;
}

extern "C" void kernel_launch(void* const* d_in, const int* in_sizes, int n_in,
                              void* d_out, int out_size, void* d_ws, size_t ws_size,
                              hipStream_t stream) {
  const float* hs    = (const float*)d_in[0];
  const int*   mask  = (const int*)d_in[1];
  const int*   shead = (const int*)d_in[2];
  const int*   stail = (const int*)d_in[3];
  const float* lw    = (const float*)d_in[4];
  const float* ln1g  = (const float*)d_in[5];
  const float* ln1b  = (const float*)d_in[6];
  const float* Wq    = (const float*)d_in[7];
  const float* bq    = (const float*)d_in[8];
  const float* Wk    = (const float*)d_in[9];
  const float* bk    = (const float*)d_in[10];
  const float* Wv    = (const float*)d_in[11];
  const float* bv    = (const float*)d_in[12];
  const float* Wo    = (const float*)d_in[13];
  const float* bo    = (const float*)d_in[14];
  const float* ln2g  = (const float*)d_in[15];
  const float* ln2b  = (const float*)d_in[16];

  char* ws = (char*)d_ws;
  u16* xb  = (u16*)(ws);                 // 32 MiB
  u16* wb  = (u16*)(ws + 33554432);      // 8 MiB (Wq,Wk,Wv,Wo bf16)
  u16* qb  = (u16*)(ws + 41943040);      // 32 MiB
  u16* kb  = (u16*)(ws + 75497472);      // 32 MiB
  u16* vt  = (u16*)(ws + 109051904);     // 32 MiB
  u16* ctx = (u16*)(ws + 142606336);     // 32 MiB ; ends at 176160768
  u16* t   = (u16*)(ws + 41943040);      // 32 MiB bf16, overlays qb (dead after attn)
  float* out = (float*)d_out;

  convw_kernel<<<dim3(1024,4),256,0,stream>>>(Wq,Wk,Wv,Wo,wb);
  mixln_kernel<<<Mn,256,0,stream>>>(hs,lw,ln1g,ln1b,xb);
  gemm256_kernel<0><<<256,512,0,stream>>>(xb, wb,           bq, nullptr, qb, 0.044194173824159223f);
  gemm256_kernel<0><<<256,512,0,stream>>>(xb, wb+1048576,   bk, nullptr, kb, 1.0f);
  gemm256_kernel<1><<<256,512,0,stream>>>(xb, wb+2097152,   bv, nullptr, vt, 1.0f);
  attn_kernel<<<256,512,0,stream>>>(qb,kb,vt,mask,ctx);
  gemm256_kernel<2><<<256,512,0,stream>>>(ctx, wb+3145728,  bo, xb, t, 1.0f);
  ln2_kernel<<<Mn,256,0,stream>>>(t, ln2g, ln2b);
  span_kernel<<<Bn*NSn,256,0,stream>>>(t, shead, stail, out);
}